// Round 1
// baseline (11.979 us; speedup 1.0000x reference)
//
#include <hip/hip_runtime.h>

// ReLU relaxation bound transformer — fully elementwise.
// bounds: [2, N] fp32 (row 0 = lb, row 1 = ub). out: [2, N] fp32.
// The reference's diag-matrix matmuls reduce to per-element products:
//   lower = beta * lb            (beta in {0,1}, clip(diag,None,0) == 0)
//   upper = lmbda * ub + mu      (lmbda >= 0)
__global__ void relu_transformer_kernel(const float* __restrict__ bounds,
                                        float* __restrict__ out, int N) {
    int t = blockIdx.x * blockDim.x + threadIdx.x;
    int idx = t * 4;
    if (idx >= N) return;

    float4 lb4 = *reinterpret_cast<const float4*>(bounds + idx);
    float4 ub4 = *reinterpret_cast<const float4*>(bounds + N + idx);
    float4 olb, oub;

    const float* lbp = reinterpret_cast<const float*>(&lb4);
    const float* ubp = reinterpret_cast<const float*>(&ub4);
    float* olbp = reinterpret_cast<float*>(&olb);
    float* oubp = reinterpret_cast<float*>(&oub);

#pragma unroll
    for (int k = 0; k < 4; ++k) {
        float lb = lbp[k];
        float ub = ubp[k];

        bool ind2 = (lb >= 0.0f);                 // stably active
        bool ind3 = (ub > 0.0f) && (lb < 0.0f);   // unstable
        bool ind4 = (ub > -lb) && ind3;           // unstable, upper-dominant

        float new_lb = (ind2 || ind4) ? lb : 0.0f;
        float new_ub = (ind2 || ind3) ? ub : 0.0f;

        float diff  = ind3 ? (ub - lb) : 1.0f;
        float lmbda = ind2 ? 1.0f : (ind3 ? (ub / diff) : 0.0f);
        float beta  = (ind2 || ind4) ? 1.0f : 0.0f;
        float mu    = ind3 ? (-lb * ub / diff) : 0.0f;

        float lower = beta * lb;            // diag(beta) @ lb, neg-clip term = 0
        float upper = lmbda * ub + mu;      // diag(lmbda) @ ub + mu

        olbp[k] = (lower > new_lb) ? lower : new_lb;
        oubp[k] = (upper < new_ub) ? upper : new_ub;
    }

    *reinterpret_cast<float4*>(out + idx) = olb;
    *reinterpret_cast<float4*>(out + N + idx) = oub;
}

extern "C" void kernel_launch(void* const* d_in, const int* in_sizes, int n_in,
                              void* d_out, int out_size, void* d_ws, size_t ws_size,
                              hipStream_t stream) {
    const float* bounds = (const float*)d_in[0];
    float* out = (float*)d_out;
    int N = in_sizes[0] / 2;            // bounds is [2, N] flat

    int threads = N / 4;                // float4 per thread
    int block = 256;
    int grid = (threads + block - 1) / block;
    relu_transformer_kernel<<<grid, block, 0, stream>>>(bounds, out, N);
}

// Round 2
// 9.746 us; speedup vs baseline: 1.2291x; 1.2291x over previous
//
#include <hip/hip_runtime.h>

// ReLU relaxation bound transformer — fully elementwise.
// bounds: [2, N] fp32 (row 0 = lb, row 1 = ub). out: [2, N] fp32.
// The reference's diag-matrix matmuls reduce to per-element products:
//   lower = beta * lb            (beta in {0,1}, clip(diag,None,0) == 0)
//   upper = lmbda * ub + mu      (lmbda >= 0)
//
// N=8192 -> 128 KB total traffic: latency/launch-bound, not BW-bound.
// 64-thread blocks spread the 2048 threads across 32 CUs to overlap
// HBM miss latency across more parallel streams.
__global__ void __launch_bounds__(64, 1)
relu_transformer_kernel(const float* __restrict__ bounds,
                        float* __restrict__ out, int N) {
    int t = blockIdx.x * blockDim.x + threadIdx.x;
    int idx = t * 4;
    if (idx >= N) return;

    // issue both independent loads up front
    float4 lb4 = *reinterpret_cast<const float4*>(bounds + idx);
    float4 ub4 = *reinterpret_cast<const float4*>(bounds + N + idx);
    float4 olb, oub;

    const float* lbp = reinterpret_cast<const float*>(&lb4);
    const float* ubp = reinterpret_cast<const float*>(&ub4);
    float* olbp = reinterpret_cast<float*>(&olb);
    float* oubp = reinterpret_cast<float*>(&oub);

#pragma unroll
    for (int k = 0; k < 4; ++k) {
        float lb = lbp[k];
        float ub = ubp[k];

        bool ind2 = (lb >= 0.0f);                 // stably active
        bool ind3 = (ub > 0.0f) && (lb < 0.0f);   // unstable
        bool ind4 = (ub > -lb) && ind3;           // unstable, upper-dominant

        float new_lb = (ind2 || ind4) ? lb : 0.0f;
        float new_ub = (ind2 || ind3) ? ub : 0.0f;

        float diff  = ind3 ? (ub - lb) : 1.0f;
        float lmbda = ind2 ? 1.0f : (ind3 ? (ub / diff) : 0.0f);
        float beta  = (ind2 || ind4) ? 1.0f : 0.0f;
        float mu    = ind3 ? (-lb * ub / diff) : 0.0f;

        float lower = beta * lb;            // diag(beta) @ lb, neg-clip term = 0
        float upper = lmbda * ub + mu;      // diag(lmbda) @ ub + mu

        olbp[k] = (lower > new_lb) ? lower : new_lb;
        oubp[k] = (upper < new_ub) ? upper : new_ub;
    }

    *reinterpret_cast<float4*>(out + idx) = olb;
    *reinterpret_cast<float4*>(out + N + idx) = oub;
}

extern "C" void kernel_launch(void* const* d_in, const int* in_sizes, int n_in,
                              void* d_out, int out_size, void* d_ws, size_t ws_size,
                              hipStream_t stream) {
    const float* bounds = (const float*)d_in[0];
    float* out = (float*)d_out;
    int N = in_sizes[0] / 2;            // bounds is [2, N] flat

    int threads = N / 4;                // float4 per thread
    int block = 64;                     // one wave per block -> 32 workgroups
    int grid = (threads + block - 1) / block;
    relu_transformer_kernel<<<grid, block, 0, stream>>>(bounds, out, N);
}

// Round 3
// 9.709 us; speedup vs baseline: 1.2339x; 1.0039x over previous
//
#include <hip/hip_runtime.h>

// ReLU relaxation bound transformer — fully elementwise.
// bounds: [2, N] fp32 (row 0 = lb, row 1 = ub). out: [2, N] fp32.
// The reference's diag-matrix matmuls reduce to per-element products:
//   lower = beta * lb            (beta in {0,1}, clip(diag,None,0) == 0)
//   upper = lmbda * ub + mu      (lmbda >= 0)
//
// N=8192 -> 128 KB total traffic: pure latency/launch-bound.
// Scalar (1 elem/thread) with 64-thread blocks -> 128 workgroups across
// 256 CUs: maximal parallel miss streams, minimal per-wave critical path.
__global__ void __launch_bounds__(64, 1)
relu_transformer_kernel(const float* __restrict__ bounds,
                        float* __restrict__ out, int N) {
    int i = blockIdx.x * blockDim.x + threadIdx.x;
    if (i >= N) return;

    float lb = bounds[i];
    float ub = bounds[N + i];

    bool ind2 = (lb >= 0.0f);                 // stably active
    bool ind3 = (ub > 0.0f) && (lb < 0.0f);   // unstable
    bool ind4 = (ub > -lb) && ind3;           // unstable, upper-dominant

    float new_lb = (ind2 || ind4) ? lb : 0.0f;
    float new_ub = (ind2 || ind3) ? ub : 0.0f;

    float diff  = ind3 ? (ub - lb) : 1.0f;
    float lmbda = ind2 ? 1.0f : (ind3 ? (ub / diff) : 0.0f);
    float beta  = (ind2 || ind4) ? 1.0f : 0.0f;
    float mu    = ind3 ? (-lb * ub / diff) : 0.0f;

    float lower = beta * lb;            // diag(beta) @ lb, neg-clip term = 0
    float upper = lmbda * ub + mu;      // diag(lmbda) @ ub + mu

    out[i]     = (lower > new_lb) ? lower : new_lb;
    out[N + i] = (upper < new_ub) ? upper : new_ub;
}

extern "C" void kernel_launch(void* const* d_in, const int* in_sizes, int n_in,
                              void* d_out, int out_size, void* d_ws, size_t ws_size,
                              hipStream_t stream) {
    const float* bounds = (const float*)d_in[0];
    float* out = (float*)d_out;
    int N = in_sizes[0] / 2;            // bounds is [2, N] flat

    int block = 64;                     // one wave per block
    int grid = (N + block - 1) / block; // 128 workgroups for N=8192
    relu_transformer_kernel<<<grid, block, 0, stream>>>(bounds, out, N);
}